// Round 3
// baseline (15518.924 us; speedup 1.0000x reference)
//
#include <hip/hip_runtime.h>
#include <hip/hip_bf16.h>

typedef __hip_bfloat16 bf16;
typedef __attribute__((ext_vector_type(8))) short short8;
typedef __attribute__((ext_vector_type(4))) float float4v;

#define B_    1024
#define H_    512
#define G4H   2048
#define F_    32
#define CIN_  4
#define K_    30
#define STRIDE_ 6
#define L_    924
#define T_    150
#define KD_   40
#define NSTEPS_ 10

__device__ __forceinline__ float sigmoidf_(float x) { return 1.f / (1.f + __expf(-x)); }
__device__ __forceinline__ float tanhf_(float x)    { return 1.f - 2.f / (__expf(2.f * x) + 1.f); }
__device__ __forceinline__ float b2f_(short s) {
    return __uint_as_float(((unsigned)(unsigned short)s) << 16);
}

struct LayerArgs {
    const bf16* X;     // [1024 x Kx], row stride = Kx (32 or 512); null => inactive
    int Kx;
    const bf16* Wih;   // [2048 x Kx]
    const bf16* Whh;   // [2048 x 512]
    const bf16* Hin;   // [1024 x 512]
    const float* bias; // [2048]
    float* C;          // [1024 x 512]
    bf16* Hout;        // [1024 x 512]
};

// ---------------------------------------------------------------------------
// fp32 -> bf16 conversion
// ---------------------------------------------------------------------------
__global__ __launch_bounds__(256) void cvt_kernel(const float* __restrict__ src,
                                                  bf16* __restrict__ dst, int n) {
    int i = blockIdx.x * 256 + threadIdx.x;
    if (i < n) dst[i] = __float2bfloat16(src[i]);
}

// ---------------------------------------------------------------------------
__global__ void bias_kernel(const float* __restrict__ bih0, const float* __restrict__ bhh0,
                            const float* __restrict__ bih1, const float* __restrict__ bhh1,
                            float* __restrict__ b0, float* __restrict__ b1) {
    int i = blockIdx.x * 256 + threadIdx.x;
    if (i < G4H)      b0[i] = bih0[i] + bhh0[i];
    else if (i < 2*G4H) { int j = i - G4H; b1[j] = bih1[j] + bhh1[j]; }
}

// ---------------------------------------------------------------------------
// encoder conv1d + relu -> seq [T, B, F] bf16
// ---------------------------------------------------------------------------
__global__ __launch_bounds__(256) void conv_kernel(
    const float* __restrict__ x,    // [B, 4, 924]
    const float* __restrict__ w,    // [32, 4, 30]
    const float* __restrict__ cb,   // [32]
    bf16* __restrict__ seq)         // [150, 1024, 32]
{
    __shared__ float w_lds[CIN_ * K_ * F_];
    __shared__ float x_lds[CIN_ * L_];
    int tid = threadIdx.x;
    int b = blockIdx.x;
    for (int i = tid; i < CIN_ * K_ * F_; i += 256) {
        int f = i & 31, r = i >> 5;
        w_lds[r * 32 + f] = w[f * (CIN_ * K_) + r];
    }
    const float* xb = x + (size_t)b * (CIN_ * L_);
    for (int i = tid; i < CIN_ * L_; i += 256)
        x_lds[i] = xb[i];
    __syncthreads();
    int f = tid & 31, tt = tid >> 5;
    float cbf = cb[f];
    for (int t0 = 0; t0 < T_; t0 += 8) {
        int t = t0 + tt;
        if (t < T_) {
            float acc = cbf;
            #pragma unroll
            for (int c = 0; c < CIN_; ++c) {
                const float* xr = x_lds + c * L_ + t * STRIDE_;
                const float* wr = w_lds + c * K_ * 32 + f;
                #pragma unroll
                for (int k = 0; k < K_; ++k)
                    acc += xr[k] * wr[k * 32];
            }
            acc = fmaxf(acc, 0.f);
            seq[(size_t)t * (B_ * F_) + b * F_ + f] = __float2bfloat16(acc);
        }
    }
}

// ---------------------------------------------------------------------------
// Fused 2-layer pipelined LSTM phase.
// Grid: 512 blocks (0..255 layer0-slot, 256..511 layer1-slot) or 256 (slot0 only).
// Block: 256 thr = 4 waves. Tile: M=128 batch rows x 16 hidden cols x 4 gates.
//   wave w: rows m0+32w .. +31 (2 msubs of 16); all 4 gates, hidden 16.
// B (weights, 64 gate-rows x Kchunk) staged in double-buffered LDS, fragment-
// major so ds_read_b128 at lane*16B is conflict-free. A-frags direct global
// (rows are wave-private). Register prefetch of chunk c+1 overlaps MFMA of c.
// ---------------------------------------------------------------------------
__global__ __launch_bounds__(256, 2) void lstm_phase(LayerArgs L0, LayerArgs L1) {
    __shared__ short8 Blds[2][512];   // [buf][(nsub*nks+ks)*64 + lane], 16 KB

    const int bid = blockIdx.x;
    LayerArgs La = (bid < 256) ? L0 : L1;
    if (La.X == nullptr) return;
    const int lb   = bid & 255;
    const int m0   = (lb >> 5) * 128;      // 8 m-tiles
    const int j0   = (lb & 31) * 16;       // 32 hidden tiles
    const int tid  = threadIdx.x;
    const int wid  = tid >> 6;
    const int lane = tid & 63;
    const int row16 = lane & 15;
    const int quad  = lane >> 4;
    const int mrow0 = m0 + wid * 32 + row16;

    const int ncx   = (La.Kx == 32) ? 1 : 8;
    const int total = ncx + 8;

    float4v acc[2][4];
    #pragma unroll
    for (int ms = 0; ms < 2; ++ms)
        #pragma unroll
        for (int g = 0; g < 4; ++g)
            acc[ms][g] = (float4v){0.f, 0.f, 0.f, 0.f};

    auto info = [&](int c, const bf16*& src, int& sstr, const bf16*& W, int& wstr,
                    int& kc, int& nks) {
        if (c < ncx) { src = La.X;  sstr = La.Kx; W = La.Wih; wstr = La.Kx;
                       kc = c * 64; nks = (La.Kx == 32) ? 1 : 2; }
        else         { src = La.Hin; sstr = H_;   W = La.Whh; wstr = H_;
                       kc = (c - ncx) * 64; nks = 2; }
    };

    short8 aF[2][2], aN[2][2], rB[2];

    // prologue: chunk 0 -> regs -> LDS buf0
    {
        const bf16* src; int sstr; const bf16* W; int wstr; int kc, nks;
        info(0, src, sstr, W, wstr, kc, nks);
        #pragma unroll
        for (int ms = 0; ms < 2; ++ms)
            #pragma unroll
            for (int ks = 0; ks < 2; ++ks)
                if (ks < nks)
                    aF[ms][ks] = *(const short8*)(src + (size_t)(mrow0 + ms*16) * sstr
                                                  + kc + ks*32 + quad*8);
        for (int i = 0; i < nks; ++i) {
            int v = tid + i * 256;
            int g = v >> 6, li = v & 63;
            int nsub = (nks == 2) ? (g >> 1) : g;
            int ks   = (nks == 2) ? (g & 1) : 0;
            rB[i] = *(const short8*)(W + (size_t)(nsub*H_ + j0 + (li & 15)) * wstr
                                     + kc + ks*32 + ((li >> 4) & 3)*8);
        }
        for (int i = 0; i < nks; ++i) Blds[0][tid + i*256] = rB[i];
        __syncthreads();
    }

    for (int c = 0; c < total; ++c) {
        const bf16* srcC; int sstrC; const bf16* WC; int wstrC; int kcC, nksC;
        info(c, srcC, sstrC, WC, wstrC, kcC, nksC);

        int nksN = 0;
        if (c + 1 < total) {
            const bf16* srcN; int sstrN; const bf16* WN; int wstrN; int kcN;
            info(c + 1, srcN, sstrN, WN, wstrN, kcN, nksN);
            #pragma unroll
            for (int ms = 0; ms < 2; ++ms)
                #pragma unroll
                for (int ks = 0; ks < 2; ++ks)
                    if (ks < nksN)
                        aN[ms][ks] = *(const short8*)(srcN + (size_t)(mrow0 + ms*16) * sstrN
                                                      + kcN + ks*32 + quad*8);
            for (int i = 0; i < nksN; ++i) {
                int v = tid + i * 256;
                int g = v >> 6, li = v & 63;
                int nsub = (nksN == 2) ? (g >> 1) : g;
                int ks   = (nksN == 2) ? (g & 1) : 0;
                rB[i] = *(const short8*)(WN + (size_t)(nsub*H_ + j0 + (li & 15)) * wstrN
                                         + kcN + ks*32 + ((li >> 4) & 3)*8);
            }
        }

        // compute chunk c
        const short8* Bbuf = Blds[c & 1];
        #pragma unroll
        for (int ks = 0; ks < 2; ++ks) {
            if (ks < nksC) {
                #pragma unroll
                for (int nsub = 0; nsub < 4; ++nsub) {
                    short8 bfr = Bbuf[(nsub * nksC + ks) * 64 + lane];
                    acc[0][nsub] = __builtin_amdgcn_mfma_f32_16x16x32_bf16(aF[0][ks], bfr, acc[0][nsub], 0, 0, 0);
                    acc[1][nsub] = __builtin_amdgcn_mfma_f32_16x16x32_bf16(aF[1][ks], bfr, acc[1][nsub], 0, 0, 0);
                }
            }
        }

        if (c + 1 < total) {
            for (int i = 0; i < nksN; ++i) Blds[(c + 1) & 1][tid + i*256] = rB[i];
            #pragma unroll
            for (int ms = 0; ms < 2; ++ms) { aF[ms][0] = aN[ms][0]; aF[ms][1] = aN[ms][1]; }
        }
        __syncthreads();
    }

    // epilogue: gates i,f,g,o -> c,h update
    const int j = j0 + row16;
    const float bi = La.bias[j];
    const float bff = La.bias[H_ + j];
    const float bg = La.bias[2*H_ + j];
    const float bo = La.bias[3*H_ + j];
    #pragma unroll
    for (int ms = 0; ms < 2; ++ms) {
        #pragma unroll
        for (int r = 0; r < 4; ++r) {
            int brow = m0 + wid*32 + ms*16 + quad*4 + r;
            float ig = sigmoidf_(acc[ms][0][r] + bi);
            float fg = sigmoidf_(acc[ms][1][r] + bff);
            float gg = tanhf_(acc[ms][2][r] + bg);
            float og = sigmoidf_(acc[ms][3][r] + bo);
            size_t idx = (size_t)brow * H_ + j;
            float cn = fg * La.C[idx] + ig * gg;
            La.C[idx] = cn;
            La.Hout[idx] = __float2bfloat16(og * tanhf_(cn));
        }
    }
}

// ---------------------------------------------------------------------------
// y = h1 @ dec_w^T + dec_b -> Y bf16 [B,32]; optionally store fut fp32
// ---------------------------------------------------------------------------
__global__ __launch_bounds__(256) void dec_kernel(
    const bf16* __restrict__ Hb,       // [B, 512] bf16
    const bf16* __restrict__ wb,       // [32, 512] bf16
    const float* __restrict__ dec_b,   // [32]
    bf16* __restrict__ Y,              // [B, 32]
    float* __restrict__ fut, int step) // [B, 32, 10]
{
    int tid = blockIdx.x * 256 + threadIdx.x;  // 32768
    int b = tid >> 5, f = tid & 31;
    const short8* h = (const short8*)(Hb + (size_t)b * H_);
    const short8* w = (const short8*)(wb + (size_t)f * H_);
    float acc = dec_b[f];
    for (int i = 0; i < H_ / 8; ++i) {
        short8 hv = h[i], wv = w[i];
        #pragma unroll
        for (int k = 0; k < 8; ++k)
            acc += b2f_(hv[k]) * b2f_(wv[k]);
    }
    Y[tid] = __float2bfloat16(acc);
    if (step >= 0) fut[(size_t)b * (F_ * NSTEPS_) + f * NSTEPS_ + step] = acc;
}

// ---------------------------------------------------------------------------
__global__ __launch_bounds__(256) void deconv_kernel(
    const float* __restrict__ fut,    // [B, 32, 10]
    const float* __restrict__ dw,     // [32, 1, 40]
    float* __restrict__ out)          // [B, 1, 49]
{
    int idx = blockIdx.x * 256 + threadIdx.x;
    if (idx >= B_ * 49) return;
    int b = idx / 49, jj = idx % 49;
    int tlo = jj - (KD_ - 1); if (tlo < 0) tlo = 0;
    int thi = jj; if (thi > NSTEPS_ - 1) thi = NSTEPS_ - 1;
    float acc = 0.f;
    for (int f = 0; f < F_; ++f) {
        const float* fr = fut + (size_t)b * (F_ * NSTEPS_) + f * NSTEPS_;
        const float* wr = dw + f * KD_;
        for (int t = tlo; t <= thi; ++t)
            acc += fr[t] * wr[jj - t];
    }
    out[idx] = acc;
}

// ---------------------------------------------------------------------------
extern "C" void kernel_launch(void* const* d_in, const int* in_sizes, int n_in,
                              void* d_out, int out_size, void* d_ws, size_t ws_size,
                              hipStream_t stream) {
    const float* x       = (const float*)d_in[0];
    const float* conv_w  = (const float*)d_in[1];
    const float* conv_b  = (const float*)d_in[2];
    const float* Wih0f   = (const float*)d_in[3];
    const float* Whh0f   = (const float*)d_in[4];
    const float* bih0    = (const float*)d_in[5];
    const float* bhh0    = (const float*)d_in[6];
    const float* Wih1f   = (const float*)d_in[7];
    const float* Whh1f   = (const float*)d_in[8];
    const float* bih1    = (const float*)d_in[9];
    const float* bhh1    = (const float*)d_in[10];
    const float* dec_wf  = (const float*)d_in[11];
    const float* dec_b   = (const float*)d_in[12];
    const float* deconvw = (const float*)d_in[13];
    float* out = (float*)d_out;

    char* ws = (char*)d_ws;
    size_t off = 0;
    auto alloc = [&](size_t bytes) { char* p = ws + off; off = (off + bytes + 255) & ~(size_t)255; return p; };
    bf16*  seq   = (bf16*) alloc((size_t)T_ * B_ * F_ * 2);
    float* b0v   = (float*)alloc(G4H * 4);
    float* b1v   = (float*)alloc(G4H * 4);
    float* c0    = (float*)alloc((size_t)B_ * H_ * 4);
    float* c1    = (float*)alloc((size_t)B_ * H_ * 4);
    bf16*  h0[2], *h1[2];
    h0[0] = (bf16*)alloc((size_t)B_ * H_ * 2);
    h0[1] = (bf16*)alloc((size_t)B_ * H_ * 2);
    h1[0] = (bf16*)alloc((size_t)B_ * H_ * 2);
    h1[1] = (bf16*)alloc((size_t)B_ * H_ * 2);
    bf16*  y     = (bf16*) alloc((size_t)B_ * F_ * 2);
    float* fut   = (float*)alloc((size_t)B_ * F_ * NSTEPS_ * 4);
    bf16*  Wih0b = (bf16*) alloc((size_t)G4H * F_ * 2);
    bf16*  Whh0b = (bf16*) alloc((size_t)G4H * H_ * 2);
    bf16*  Wih1b = (bf16*) alloc((size_t)G4H * H_ * 2);
    bf16*  Whh1b = (bf16*) alloc((size_t)G4H * H_ * 2);
    bf16*  dec_wb= (bf16*) alloc((size_t)F_ * H_ * 2);

    hipMemsetAsync(c0, 0, (size_t)B_ * H_ * 4, stream);
    hipMemsetAsync(c1, 0, (size_t)B_ * H_ * 4, stream);
    hipMemsetAsync(h0[1], 0, (size_t)B_ * H_ * 2, stream);
    hipMemsetAsync(h1[1], 0, (size_t)B_ * H_ * 2, stream);

    cvt_kernel<<<(G4H * F_ + 255) / 256, 256, 0, stream>>>(Wih0f, Wih0b, G4H * F_);
    cvt_kernel<<<(G4H * H_ + 255) / 256, 256, 0, stream>>>(Whh0f, Whh0b, G4H * H_);
    cvt_kernel<<<(G4H * H_ + 255) / 256, 256, 0, stream>>>(Wih1f, Wih1b, G4H * H_);
    cvt_kernel<<<(G4H * H_ + 255) / 256, 256, 0, stream>>>(Whh1f, Whh1b, G4H * H_);
    cvt_kernel<<<(F_ * H_ + 255) / 256, 256, 0, stream>>>(dec_wf, dec_wb, F_ * H_);

    bias_kernel<<<16, 256, 0, stream>>>(bih0, bhh0, bih1, bhh1, b0v, b1v);
    conv_kernel<<<B_, 256, 0, stream>>>(x, conv_w, conv_b, seq);

    LayerArgs nul; nul.X = nullptr; nul.Kx = 0; nul.Wih = nullptr; nul.Whh = nullptr;
    nul.Hin = nullptr; nul.bias = nullptr; nul.C = nullptr; nul.Hout = nullptr;
    auto mk = [&](const bf16* X, int Kx, const bf16* Wih, const bf16* Whh,
                  const bf16* Hin, const float* bias, float* C, bf16* Hout) {
        LayerArgs a; a.X = X; a.Kx = Kx; a.Wih = Wih; a.Whh = Whh;
        a.Hin = Hin; a.bias = bias; a.C = C; a.Hout = Hout; return a;
    };

    // encoder: pipelined phases p = 0..150; layer0 does t=p, layer1 does t=p-1
    for (int p = 0; p <= T_; ++p) {
        LayerArgs a0 = nul, a1 = nul;
        if (p < T_)
            a0 = mk(seq + (size_t)p * B_ * F_, F_, Wih0b, Whh0b,
                    h0[(p + 1) & 1], b0v, c0, h0[p & 1]);
        if (p >= 1) {
            int t1 = p - 1;
            a1 = mk(h0[t1 & 1], H_, Wih1b, Whh1b,
                    h1[(t1 + 1) & 1], b1v, c1, h1[t1 & 1]);
        }
        if (p >= 1 && p < T_)
            lstm_phase<<<512, 256, 0, stream>>>(a0, a1);
        else if (p < T_)
            lstm_phase<<<256, 256, 0, stream>>>(a0, nul);
        else
            lstm_phase<<<256, 256, 0, stream>>>(a1, nul);
    }

    // decoder: strictly serial y -> l0 -> l1 chain
    dec_kernel<<<128, 256, 0, stream>>>(h1[1], dec_wb, dec_b, y, fut, -1);
    for (int s = 0; s < NSTEPS_; ++s) {
        int t = T_ + s;
        LayerArgs a0 = mk(y, F_, Wih0b, Whh0b, h0[(t + 1) & 1], b0v, c0, h0[t & 1]);
        lstm_phase<<<256, 256, 0, stream>>>(a0, nul);
        LayerArgs a1 = mk(h0[t & 1], H_, Wih1b, Whh1b, h1[(t + 1) & 1], b1v, c1, h1[t & 1]);
        lstm_phase<<<256, 256, 0, stream>>>(a1, nul);
        dec_kernel<<<128, 256, 0, stream>>>(h1[t & 1], dec_wb, dec_b, y, fut, s);
    }
    deconv_kernel<<<196, 256, 0, stream>>>(fut, deconvw, out);
}